// Round 17
// baseline (398.417 us; speedup 1.0000x reference)
//
#include <hip/hip_runtime.h>
#include <hip/hip_cooperative_groups.h>

namespace cg = cooperative_groups;

#define T_DIM 200
#define U_DIM 100
#define D_DIM 512
#define V_DIM 1024
#define TU_DIM (T_DIM * U_DIM)   // 20000
#define M_TOTAL (8 * TU_DIM)     // 160000 rows
#define M_TILE 64                // fallback kernel tile
#define NTILES 10000             // 1250 mt x 8 nt
#define PBLK 512                 // persistent blocks (2/CU)

typedef __attribute__((ext_vector_type(8))) short bf16x8;
typedef __attribute__((ext_vector_type(4))) float f32x4;

__device__ __forceinline__ unsigned short f2bf(float f) {
    unsigned int u = __float_as_uint(f);
    u += 0x7FFFu + ((u >> 16) & 1u);   // RNE to bf16
    return (unsigned short)(u >> 16);
}

__device__ __forceinline__ float fast_tanh(float x) {
    float e = __expf(2.0f * x);
    return 1.0f - 2.0f / (e + 1.0f);
}

__device__ __forceinline__ void row_ptrs(int g, const float* enc, const int* prefix,
                                         const float* emb, const float** encp, const float** embp) {
    const int b = g / TU_DIM;
    const int m = g - b * TU_DIM;
    const int t = m / U_DIM;
    const int u = m - t * U_DIM;
    *encp = enc + (size_t)(b * T_DIM + t) * D_DIM;
    *embp = emb + (size_t)prefix[b * U_DIM + u] * D_DIM;
}

__device__ __forceinline__ void mat_a_row8(const float* encp, const float* embp,
                                           unsigned short* ap, int d) {
    float4 e0 = *reinterpret_cast<const float4*>(encp + d);
    float4 e1 = *reinterpret_cast<const float4*>(encp + d + 4);
    float4 p0 = *reinterpret_cast<const float4*>(embp + d);
    float4 p1 = *reinterpret_cast<const float4*>(embp + d + 4);
    bf16x8 pk;
    pk[0] = (short)f2bf(fast_tanh(e0.x + p0.x));
    pk[1] = (short)f2bf(fast_tanh(e0.y + p0.y));
    pk[2] = (short)f2bf(fast_tanh(e0.z + p0.z));
    pk[3] = (short)f2bf(fast_tanh(e0.w + p0.w));
    pk[4] = (short)f2bf(fast_tanh(e1.x + p1.x));
    pk[5] = (short)f2bf(fast_tanh(e1.y + p1.y));
    pk[6] = (short)f2bf(fast_tanh(e1.z + p1.z));
    pk[7] = (short)f2bf(fast_tanh(e1.w + p1.w));
    *reinterpret_cast<bf16x8*>(&ap[d]) = pk;
}

#define GLOAD_LDS16(gp, lp) \
    __builtin_amdgcn_global_load_lds( \
        (const __attribute__((address_space(1))) unsigned int*)(gp), \
        (__attribute__((address_space(3))) unsigned int*)(lp), 16, 0, 0)

// ==== cooperative persistent kernel: producer phase + grid.sync + GEMM tile loop ====
__global__ __launch_bounds__(256, 2)
void fused_kernel(const float* __restrict__ enc, const int* __restrict__ prefix,
                  const float* __restrict__ emb, const float* __restrict__ w,
                  const float* __restrict__ bias, float* __restrict__ out,
                  unsigned short* __restrict__ wbf, unsigned short* __restrict__ Abf) {
    __shared__ unsigned short ldsA[2][128 * 64];   // 2 x 16 KiB
    __shared__ unsigned short ldsB[2][128 * 64];   // 2 x 16 KiB  (total 64 KiB)

    const int tid  = threadIdx.x;
    const int lane = tid & 63;
    const int wid  = tid >> 6;               // 4 waves: 2m x 2n
    const int wm   = (wid >> 1) * 64;
    const int wn   = (wid & 1) * 64;
    const int lr   = lane & 15;
    const int lg   = lane >> 4;

    // ---------- Phase 1: producer (W convert + A materialize) ----------
    {
        // W: 131072 ushort4 chunks, 1 per thread
        const int i = blockIdx.x * 256 + tid;
        float4 v = reinterpret_cast<const float4*>(w)[i];
        ushort4 o;
        o.x = f2bf(v.x); o.y = f2bf(v.y); o.z = f2bf(v.z); o.w = f2bf(v.w);
        reinterpret_cast<ushort4*>(wbf)[i] = o;
        // A: 5000 groups of 32 rows, grid-stride
        const int rsub8 = tid >> 3;          // 0..31
        const int q = tid & 7;
        for (int g = blockIdx.x; g < 5000; g += PBLK) {
            const int rl = g * 32 + rsub8;
            const float *encp, *embp;
            row_ptrs(rl, enc, prefix, emb, &encp, &embp);
            unsigned short* ap = Abf + (size_t)rl * D_DIM;
#pragma unroll
            for (int jj = 0; jj < 8; ++jj)
                mat_a_row8(encp, embp, ap, q * 8 + jj * 64);
        }
    }
    __threadfence();                          // device-scope visibility across XCDs
    cg::this_grid().sync();

    // ---------- Phase 2: persistent GEMM tile loop (champion per-tile body) ----------
    const int rsub = tid >> 3;                // 0..31
    const int csw  = ((tid & 7) ^ (rsub & 7)) * 8;
    const unsigned short* ldsA0 = &ldsA[0][(wm + lr) * 64 + ((lg ^ (lr & 7)) * 8)];
    const unsigned short* ldsB0 = &ldsB[0][(wn + lr) * 64 + ((lg ^ (lr & 7)) * 8)];
    const int kk1off = ((((4 | lg) ^ (lr & 7)) - (lg ^ (lr & 7))) * 8);

#pragma unroll 1
    for (int tile = blockIdx.x; tile < NTILES; tile += PBLK) {
        // XCD swizzle: tile%8 constant per block -> same-XCD band as champion
        const int wgid = (tile & 7) * 1250 + (tile >> 3);
        const int mt = wgid >> 3, nt = wgid & 7;
        const int row0 = mt * 128, col0 = nt * 128;

        const unsigned short* aSt = Abf + (size_t)(row0 + rsub) * D_DIM + csw;
        const unsigned short* wSt = wbf + (size_t)(col0 + rsub) * D_DIM + csw;

        auto stage = [&](int buf, int kt) {   // 8 gload_lds per thread
            const int k0 = kt * 64;
#pragma unroll
            for (int i = 0; i < 4; ++i)
                GLOAD_LDS16(aSt + (size_t)(i * 32) * D_DIM + k0,
                            &ldsA[buf][(i * 32 + wid * 8) * 64]);
#pragma unroll
            for (int i = 0; i < 4; ++i)
                GLOAD_LDS16(wSt + (size_t)(i * 32) * D_DIM + k0,
                            &ldsB[buf][(i * 32 + wid * 8) * 64]);
        };

        f32x4 acc[4][4];
#pragma unroll
        for (int mi = 0; mi < 4; ++mi)
#pragma unroll
            for (int ni = 0; ni < 4; ++ni)
                acc[mi][ni] = (f32x4){0.f, 0.f, 0.f, 0.f};

        auto compute = [&](int buf) {
            const unsigned short* pA = ldsA0 + buf * (128 * 64);
            const unsigned short* pB = ldsB0 + buf * (128 * 64);
#pragma unroll
            for (int kk = 0; kk < 2; ++kk) {
                const int ko = kk ? kk1off : 0;
                bf16x8 bfr[4];
#pragma unroll
                for (int ni = 0; ni < 4; ++ni)
                    bfr[ni] = *reinterpret_cast<const bf16x8*>(pB + ni * (16 * 64) + ko);
                __builtin_amdgcn_s_setprio(1);
#pragma unroll
                for (int mi = 0; mi < 4; ++mi) {
                    bf16x8 af = *reinterpret_cast<const bf16x8*>(pA + mi * (16 * 64) + ko);
#pragma unroll
                    for (int ni = 0; ni < 4; ++ni)
                        acc[mi][ni] = __builtin_amdgcn_mfma_f32_16x16x32_bf16(af, bfr[ni], acc[mi][ni], 0, 0, 0);
                }
                __builtin_amdgcn_s_setprio(0);
            }
        };

        stage(0, 0);
        stage(1, 1);
        // vmcnt(8): prior-tile epilogue stores (older in FIFO) also drained -> safe
#pragma unroll 1
        for (int it = 0; it < 4; ++it) {
            asm volatile("s_waitcnt vmcnt(8)" ::: "memory");   // tile 2it landed
            __builtin_amdgcn_s_barrier();
            compute(0);
            asm volatile("s_waitcnt lgkmcnt(0)" ::: "memory");
            __builtin_amdgcn_s_barrier();                      // buf0 free
            if (it < 3) stage(0, 2 * it + 2);
            if (it < 3) asm volatile("s_waitcnt vmcnt(8)" ::: "memory");
            else        asm volatile("s_waitcnt vmcnt(0)" ::: "memory");
            __builtin_amdgcn_s_barrier();
            compute(1);
            if (it < 3) {
                asm volatile("s_waitcnt lgkmcnt(0)" ::: "memory");
                __builtin_amdgcn_s_barrier();                  // buf1 free
                stage(1, 2 * it + 3);
            }
        }

        // epilogue: bias + nontemporal scattered store (champion)
        float bv[4];
#pragma unroll
        for (int ni = 0; ni < 4; ++ni)
            bv[ni] = bias[col0 + wn + ni * 16 + lr];
#pragma unroll
        for (int mi = 0; mi < 4; ++mi) {
#pragma unroll
            for (int j = 0; j < 4; ++j) {
                const long long row = (long long)row0 + wm + mi * 16 + lg * 4 + j;
                float* op = out + row * V_DIM + col0 + wn;
#pragma unroll
                for (int ni = 0; ni < 4; ++ni)
                    __builtin_nontemporal_store(acc[mi][ni][j] + bv[ni], &op[ni * 16 + lr]);
            }
        }
        __builtin_amdgcn_s_barrier();          // keep waves phase-locked into next tile
    }
}

// ==== champion three-kernel path (r10/r16, used if cooperative launch unavailable) ====
__global__ void conv_w_kernel(const float* __restrict__ w, ushort4* __restrict__ wbf) {
    int i = blockIdx.x * blockDim.x + threadIdx.x;
    float4 v = reinterpret_cast<const float4*>(w)[i];
    ushort4 o;
    o.x = f2bf(v.x); o.y = f2bf(v.y); o.z = f2bf(v.z); o.w = f2bf(v.w);
    wbf[i] = o;
}

__global__ __launch_bounds__(512)
void mat_a_kernel(const float* __restrict__ enc, const int* __restrict__ prefix,
                  const float* __restrict__ emb, unsigned short* __restrict__ Abf) {
    const int tid = threadIdx.x;
    const int r = tid >> 3;
    const int q = tid & 7;
    const int rl = blockIdx.x * 64 + r;
    const float *encp, *embp;
    row_ptrs(rl, enc, prefix, emb, &encp, &embp);
    unsigned short* ap = Abf + (size_t)rl * D_DIM;
#pragma unroll
    for (int jj = 0; jj < 8; ++jj)
        mat_a_row8(encp, embp, ap, q * 8 + jj * 64);
}

__global__ __launch_bounds__(256, 2)
void gemm128_kernel(const unsigned short* __restrict__ Abf, const unsigned short* __restrict__ wbf,
                    const float* __restrict__ bias, float* __restrict__ out) {
    __shared__ unsigned short ldsA[2][128 * 64];
    __shared__ unsigned short ldsB[2][128 * 64];

    const int tid  = threadIdx.x;
    const int lane = tid & 63;
    const int wid  = tid >> 6;
    const int wm   = (wid >> 1) * 64;
    const int wn   = (wid & 1) * 64;
    const int lr   = lane & 15;
    const int lg   = lane >> 4;

    const int orig = blockIdx.x;
    const int wgid = (orig & 7) * 1250 + (orig >> 3);
    const int mt = wgid >> 3, nt = wgid & 7;
    const int row0 = mt * 128, col0 = nt * 128;

    const int rsub = tid >> 3;
    const int csw  = ((tid & 7) ^ (rsub & 7)) * 8;
    const unsigned short* aSt = Abf + (size_t)(row0 + rsub) * D_DIM + csw;
    const unsigned short* wSt = wbf + (size_t)(col0 + rsub) * D_DIM + csw;

    auto stage = [&](int buf, int kt) {
        const int k0 = kt * 64;
#pragma unroll
        for (int i = 0; i < 4; ++i)
            GLOAD_LDS16(aSt + (size_t)(i * 32) * D_DIM + k0,
                        &ldsA[buf][(i * 32 + wid * 8) * 64]);
#pragma unroll
        for (int i = 0; i < 4; ++i)
            GLOAD_LDS16(wSt + (size_t)(i * 32) * D_DIM + k0,
                        &ldsB[buf][(i * 32 + wid * 8) * 64]);
    };

    const unsigned short* ldsA0 = &ldsA[0][(wm + lr) * 64 + ((lg ^ (lr & 7)) * 8)];
    const unsigned short* ldsB0 = &ldsB[0][(wn + lr) * 64 + ((lg ^ (lr & 7)) * 8)];
    const int kk1off = ((((4 | lg) ^ (lr & 7)) - (lg ^ (lr & 7))) * 8);

    f32x4 acc[4][4];
#pragma unroll
    for (int mi = 0; mi < 4; ++mi)
#pragma unroll
        for (int ni = 0; ni < 4; ++ni)
            acc[mi][ni] = (f32x4){0.f, 0.f, 0.f, 0.f};

    auto compute = [&](int buf) {
        const unsigned short* pA = ldsA0 + buf * (128 * 64);
        const unsigned short* pB = ldsB0 + buf * (128 * 64);
#pragma unroll
        for (int kk = 0; kk < 2; ++kk) {
            const int ko = kk ? kk1off : 0;
            bf16x8 bfr[4];
#pragma unroll
            for (int ni = 0; ni < 4; ++ni)
                bfr[ni] = *reinterpret_cast<const bf16x8*>(pB + ni * (16 * 64) + ko);
            __builtin_amdgcn_s_setprio(1);
#pragma unroll
            for (int mi = 0; mi < 4; ++mi) {
                bf16x8 af = *reinterpret_cast<const bf16x8*>(pA + mi * (16 * 64) + ko);
#pragma unroll
                for (int ni = 0; ni < 4; ++ni)
                    acc[mi][ni] = __builtin_amdgcn_mfma_f32_16x16x32_bf16(af, bfr[ni], acc[mi][ni], 0, 0, 0);
            }
            __builtin_amdgcn_s_setprio(0);
        }
    };

    stage(0, 0);
    stage(1, 1);

#pragma unroll 1
    for (int it = 0; it < 4; ++it) {
        asm volatile("s_waitcnt vmcnt(8)" ::: "memory");
        __builtin_amdgcn_s_barrier();
        compute(0);
        asm volatile("s_waitcnt lgkmcnt(0)" ::: "memory");
        __builtin_amdgcn_s_barrier();
        if (it < 3) stage(0, 2 * it + 2);
        if (it < 3) asm volatile("s_waitcnt vmcnt(8)" ::: "memory");
        else        asm volatile("s_waitcnt vmcnt(0)" ::: "memory");
        __builtin_amdgcn_s_barrier();
        compute(1);
        if (it < 3) {
            asm volatile("s_waitcnt lgkmcnt(0)" ::: "memory");
            __builtin_amdgcn_s_barrier();
            stage(1, 2 * it + 3);
        }
    }

    float bv[4];
#pragma unroll
    for (int ni = 0; ni < 4; ++ni)
        bv[ni] = bias[col0 + wn + ni * 16 + lr];
#pragma unroll
    for (int mi = 0; mi < 4; ++mi) {
#pragma unroll
        for (int j = 0; j < 4; ++j) {
            const long long row = (long long)row0 + wm + mi * 16 + lg * 4 + j;
            float* op = out + row * V_DIM + col0 + wn;
#pragma unroll
            for (int ni = 0; ni < 4; ++ni)
                __builtin_nontemporal_store(acc[mi][ni][j] + bv[ni], &op[ni * 16 + lr]);
        }
    }
}

// ---- fused fallback (proven r3/r6) for small workspace ----
__global__ __launch_bounds__(512, 2)
void joiner_kernel(const float* __restrict__ enc, const int* __restrict__ prefix,
                   const float* __restrict__ emb, const unsigned short* __restrict__ wbf,
                   const float* __restrict__ bias, float* __restrict__ out) {
    __shared__ unsigned short A_s[M_TILE * 512];
    const int tid = threadIdx.x;
    const long long g0 = (long long)blockIdx.x * M_TILE;
    {
        const int r = tid >> 3, q = tid & 7;
        const float *encp, *embp;
        row_ptrs((int)g0 + r, enc, prefix, emb, &encp, &embp);
        const int r7 = r & 7;
#pragma unroll
        for (int jj = 0; jj < 8; ++jj) {
            const int d = q * 8 + jj * 64;
            float4 e0 = *reinterpret_cast<const float4*>(encp + d);
            float4 e1 = *reinterpret_cast<const float4*>(encp + d + 4);
            float4 p0 = *reinterpret_cast<const float4*>(embp + d);
            float4 p1 = *reinterpret_cast<const float4*>(embp + d + 4);
            bf16x8 pk;
            pk[0] = (short)f2bf(fast_tanh(e0.x + p0.x));
            pk[1] = (short)f2bf(fast_tanh(e0.y + p0.y));
            pk[2] = (short)f2bf(fast_tanh(e0.z + p0.z));
            pk[3] = (short)f2bf(fast_tanh(e0.w + p0.w));
            pk[4] = (short)f2bf(fast_tanh(e1.x + p1.x));
            pk[5] = (short)f2bf(fast_tanh(e1.y + p1.y));
            pk[6] = (short)f2bf(fast_tanh(e1.z + p1.z));
            pk[7] = (short)f2bf(fast_tanh(e1.w + p1.w));
            const int chunk = (q + 8 * jj) ^ r7;
            *reinterpret_cast<bf16x8*>(&A_s[r * 512 + chunk * 8]) = pk;
        }
    }
    __syncthreads();
    const int lane = tid & 63, wid = tid >> 6;
    const int wn = wid * 128, lr = lane & 15, lg = lane >> 4;
    const unsigned short* wb = wbf + (size_t)(wn + lr) * D_DIM + lg * 8;
    f32x4 acc[4][8];
#pragma unroll
    for (int mi = 0; mi < 4; ++mi)
#pragma unroll
        for (int ni = 0; ni < 8; ++ni) acc[mi][ni] = (f32x4){0.f, 0.f, 0.f, 0.f};
    bf16x8 bb[2][8];
#pragma unroll
    for (int ni = 0; ni < 8; ++ni)
        bb[0][ni] = *reinterpret_cast<const bf16x8*>(wb + ni * 16 * D_DIM);
#pragma unroll
    for (int s = 0; s < 16; ++s) {
        const int cur = s & 1, nxt = cur ^ 1;
        if (s < 15) {
#pragma unroll
            for (int ni = 0; ni < 8; ++ni)
                bb[nxt][ni] = *reinterpret_cast<const bf16x8*>(wb + ni * 16 * D_DIM + (s + 1) * 32);
        }
        bf16x8 af[4];
#pragma unroll
        for (int mi = 0; mi < 4; ++mi) {
            const int row = mi * 16 + lr;
            const int chunk = (s * 4 + lg) ^ (row & 7);
            af[mi] = *reinterpret_cast<const bf16x8*>(&A_s[row * 512 + chunk * 8]);
        }
#pragma unroll
        for (int mi = 0; mi < 4; ++mi)
#pragma unroll
            for (int ni = 0; ni < 8; ++ni)
                acc[mi][ni] = __builtin_amdgcn_mfma_f32_16x16x32_bf16(af[mi], bb[cur][ni], acc[mi][ni], 0, 0, 0);
    }
    float bv[8];
#pragma unroll
    for (int ni = 0; ni < 8; ++ni) bv[ni] = bias[wn + ni * 16 + lr];
#pragma unroll
    for (int mi = 0; mi < 4; ++mi) {
#pragma unroll
        for (int j = 0; j < 4; ++j) {
            const long long row = g0 + mi * 16 + lg * 4 + j;
            float* op = out + row * V_DIM + wn;
#pragma unroll
            for (int ni = 0; ni < 8; ++ni)
                op[ni * 16 + lr] = acc[mi][ni][j] + bv[ni];
        }
    }
}

extern "C" void kernel_launch(void* const* d_in, const int* in_sizes, int n_in,
                              void* d_out, int out_size, void* d_ws, size_t ws_size,
                              hipStream_t stream) {
    const float* enc    = (const float*)d_in[0];   // (8,200,512) f32
    const int*   prefix = (const int*)d_in[1];     // (8,100) int
    const float* emb    = (const float*)d_in[2];   // (1024,512) f32
    const float* jw     = (const float*)d_in[3];   // (1024,512) f32
    const float* jb     = (const float*)d_in[4];   // (1024,) f32
    float* out = (float*)d_out;                    // (8,200,100,1024) f32

    unsigned short* wbf = (unsigned short*)d_ws;   // ws[0..1MB): W bf16 row-major
    const size_t WB = (size_t)V_DIM * D_DIM * sizeof(unsigned short);
    const size_t AB = (size_t)M_TOTAL * D_DIM * sizeof(unsigned short);  // 164 MB
    unsigned short* Abf = wbf + (size_t)V_DIM * D_DIM;

    if (ws_size >= WB + AB) {
        // cooperative persistent path; fall back to champion 3-kernel path on error
        void* args[] = {(void*)&enc, (void*)&prefix, (void*)&emb, (void*)&jw,
                        (void*)&jb,  (void*)&out,    (void*)&wbf, (void*)&Abf};
        hipError_t err = hipLaunchCooperativeKernel((const void*)fused_kernel,
                                                    dim3(PBLK), dim3(256), args, 0, stream);
        if (err != hipSuccess) {
            conv_w_kernel<<<512, 256, 0, stream>>>(jw, (ushort4*)wbf);
            mat_a_kernel<<<M_TOTAL / 64, 512, 0, stream>>>(enc, prefix, emb, Abf);
            gemm128_kernel<<<NTILES, 256, 0, stream>>>(Abf, wbf, jb, out);
        }
    } else {                                       // fused fallback (proven 382/420 us)
        conv_w_kernel<<<512, 256, 0, stream>>>(jw, (ushort4*)wbf);
        joiner_kernel<<<M_TOTAL / M_TILE, 512, 0, stream>>>(enc, prefix, emb, wbf, jb, out);
    }
}

// Round 18
// 272.040 us; speedup vs baseline: 1.4646x; 1.4646x over previous
//
#include <hip/hip_runtime.h>

#define T_DIM 200
#define U_DIM 100
#define D_DIM 512
#define V_DIM 1024
#define TU_DIM (T_DIM * U_DIM)   // 20000
#define M_TOTAL (8 * TU_DIM)     // 160000 rows
#define M_TILE 64                // fallback kernel tile
#define A_BLOCKS (M_TOTAL / 64)  // 2500
#define W_BLOCKS 512             // 512 * 256 threads * 16B = 2 MB = W f32

typedef __attribute__((ext_vector_type(8))) short bf16x8;
typedef __attribute__((ext_vector_type(4))) float f32x4;

__device__ __forceinline__ unsigned short f2bf(float f) {
    unsigned int u = __float_as_uint(f);
    u += 0x7FFFu + ((u >> 16) & 1u);   // RNE to bf16
    return (unsigned short)(u >> 16);
}

__device__ __forceinline__ float fast_tanh(float x) {
    float e = __expf(2.0f * x);
    return 1.0f - 2.0f / (e + 1.0f);
}

__device__ __forceinline__ void row_ptrs(int g, const float* enc, const int* prefix,
                                         const float* emb, const float** encp, const float** embp) {
    const int b = g / TU_DIM;
    const int m = g - b * TU_DIM;
    const int t = m / U_DIM;
    const int u = m - t * U_DIM;
    *encp = enc + (size_t)(b * T_DIM + t) * D_DIM;
    *embp = emb + (size_t)prefix[b * U_DIM + u] * D_DIM;
}

__device__ __forceinline__ void mat_a_row8(const float* encp, const float* embp,
                                           unsigned short* ap, int d) {
    float4 e0 = *reinterpret_cast<const float4*>(encp + d);
    float4 e1 = *reinterpret_cast<const float4*>(encp + d + 4);
    float4 p0 = *reinterpret_cast<const float4*>(embp + d);
    float4 p1 = *reinterpret_cast<const float4*>(embp + d + 4);
    bf16x8 pk;
    pk[0] = (short)f2bf(fast_tanh(e0.x + p0.x));
    pk[1] = (short)f2bf(fast_tanh(e0.y + p0.y));
    pk[2] = (short)f2bf(fast_tanh(e0.z + p0.z));
    pk[3] = (short)f2bf(fast_tanh(e0.w + p0.w));
    pk[4] = (short)f2bf(fast_tanh(e1.x + p1.x));
    pk[5] = (short)f2bf(fast_tanh(e1.y + p1.y));
    pk[6] = (short)f2bf(fast_tanh(e1.z + p1.z));
    pk[7] = (short)f2bf(fast_tanh(e1.w + p1.w));
    *reinterpret_cast<bf16x8*>(&ap[d]) = pk;   // REGULAR store: keep A L2/L3-resident
}

// ---- merged prep: blocks [0,aBlocks) materialize A (512 thr); last W_BLOCKS convert W ----
__global__ __launch_bounds__(512)
void prep_kernel(const float* __restrict__ enc, const int* __restrict__ prefix,
                 const float* __restrict__ emb, const float* __restrict__ w,
                 unsigned short* __restrict__ Abf, ushort4* __restrict__ wbf, int aBlocks) {
    const int tid = threadIdx.x;
    if ((int)blockIdx.x >= aBlocks) {      // W convert: f32 -> bf16 row-major (256 chunks/blk... 512thr)
        const int base = (blockIdx.x - aBlocks) * 256;   // 512 blocks x 256 ushort4 = 131072
        if (tid < 256) {
            const int i = base + tid;
            float4 v = reinterpret_cast<const float4*>(w)[i];
            ushort4 o;
            o.x = f2bf(v.x); o.y = f2bf(v.y); o.z = f2bf(v.z); o.w = f2bf(v.w);
            wbf[i] = o;
        }
        return;
    }
    // A materialize: Abf[row][512] = bf16(tanh(enc+emb))
    const int r = tid >> 3;
    const int q = tid & 7;
    const int rl = blockIdx.x * 64 + r;
    const float *encp, *embp;
    row_ptrs(rl, enc, prefix, emb, &encp, &embp);
    unsigned short* ap = Abf + (size_t)rl * D_DIM;
#pragma unroll
    for (int jj = 0; jj < 8; ++jj)
        mat_a_row8(encp, embp, ap, q * 8 + jj * 64);
}

#define GLOAD_LDS16(gp, lp) \
    __builtin_amdgcn_global_load_lds( \
        (const __attribute__((address_space(1))) unsigned int*)(gp), \
        (__attribute__((address_space(3))) unsigned int*)(lp), 16, 0, 0)

// ---- 128x128 4-wave GEMM, BK=64, 64KB LDS -> 2 blocks/CU, champion wait protocol ----
__global__ __launch_bounds__(256, 2)
void gemm128_kernel(const unsigned short* __restrict__ Abf, const unsigned short* __restrict__ wbf,
                    const float* __restrict__ bias, float* __restrict__ out) {
    __shared__ unsigned short ldsA[2][128 * 64];   // 2 x 16 KiB
    __shared__ unsigned short ldsB[2][128 * 64];   // 2 x 16 KiB  (total 64 KiB)

    const int tid  = threadIdx.x;
    const int lane = tid & 63;
    const int wid  = tid >> 6;               // 4 waves: 2m x 2n
    const int wm   = (wid >> 1) * 64;
    const int wn   = (wid & 1) * 64;
    const int lr   = lane & 15;
    const int lg   = lane >> 4;

    // XCD swizzle: nwg = 10000 (%8==0) -> contiguous 1250-block band per XCD
    const int orig = blockIdx.x;
    const int wgid = (orig & 7) * 1250 + (orig >> 3);
    const int mt = wgid >> 3, nt = wgid & 7;  // nt-inner: 8 consecutive blocks share A panel
    const int row0 = mt * 128, col0 = nt * 128;

    // staging: thread covers rows i*32 + (tid>>3); source chunk XOR-swizzled, LDS linear
    const int rsub = tid >> 3;                // 0..31
    const int csw  = ((tid & 7) ^ (rsub & 7)) * 8;
    const unsigned short* aSt = Abf + (size_t)(row0 + rsub) * D_DIM + csw;
    const unsigned short* wSt = wbf + (size_t)(col0 + rsub) * D_DIM + csw;

    auto stage = [&](int buf, int kt) {       // 8 gload_lds per thread
        const int k0 = kt * 64;
#pragma unroll
        for (int i = 0; i < 4; ++i)
            GLOAD_LDS16(aSt + (size_t)(i * 32) * D_DIM + k0,
                        &ldsA[buf][(i * 32 + wid * 8) * 64]);
#pragma unroll
        for (int i = 0; i < 4; ++i)
            GLOAD_LDS16(wSt + (size_t)(i * 32) * D_DIM + k0,
                        &ldsB[buf][(i * 32 + wid * 8) * 64]);
    };

    // lean LDS read bases: row&7 == lr&7 for all fragments -> base + compile-time imm
    const unsigned short* ldsA0 = &ldsA[0][(wm + lr) * 64 + ((lg ^ (lr & 7)) * 8)];
    const unsigned short* ldsB0 = &ldsB[0][(wn + lr) * 64 + ((lg ^ (lr & 7)) * 8)];
    const int kk1off = ((((4 | lg) ^ (lr & 7)) - (lg ^ (lr & 7))) * 8);

    f32x4 acc[4][4];
#pragma unroll
    for (int mi = 0; mi < 4; ++mi)
#pragma unroll
        for (int ni = 0; ni < 4; ++ni)
            acc[mi][ni] = (f32x4){0.f, 0.f, 0.f, 0.f};

    auto compute = [&](int buf) {
        const unsigned short* pA = ldsA0 + buf * (128 * 64);
        const unsigned short* pB = ldsB0 + buf * (128 * 64);
#pragma unroll
        for (int kk = 0; kk < 2; ++kk) {
            const int ko = kk ? kk1off : 0;
            bf16x8 bfr[4];
#pragma unroll
            for (int ni = 0; ni < 4; ++ni)
                bfr[ni] = *reinterpret_cast<const bf16x8*>(pB + ni * (16 * 64) + ko);
            __builtin_amdgcn_s_setprio(1);
#pragma unroll
            for (int mi = 0; mi < 4; ++mi) {
                bf16x8 af = *reinterpret_cast<const bf16x8*>(pA + mi * (16 * 64) + ko);
#pragma unroll
                for (int ni = 0; ni < 4; ++ni)
                    acc[mi][ni] = __builtin_amdgcn_mfma_f32_16x16x32_bf16(af, bfr[ni], acc[mi][ni], 0, 0, 0);
            }
            __builtin_amdgcn_s_setprio(0);
        }
    };

    stage(0, 0);
    stage(1, 1);

#pragma unroll 1
    for (int it = 0; it < 4; ++it) {
        asm volatile("s_waitcnt vmcnt(8)" ::: "memory");   // tile 2it landed
        __builtin_amdgcn_s_barrier();
        compute(0);
        asm volatile("s_waitcnt lgkmcnt(0)" ::: "memory");
        __builtin_amdgcn_s_barrier();                      // buf0 free
        if (it < 3) stage(0, 2 * it + 2);
        if (it < 3) asm volatile("s_waitcnt vmcnt(8)" ::: "memory");
        else        asm volatile("s_waitcnt vmcnt(0)" ::: "memory");
        __builtin_amdgcn_s_barrier();
        compute(1);
        if (it < 3) {
            asm volatile("s_waitcnt lgkmcnt(0)" ::: "memory");
            __builtin_amdgcn_s_barrier();                  // buf1 free
            stage(1, 2 * it + 3);
        }
    }

    // epilogue: bias + nontemporal scattered store (r10-proven)
    float bv[4];
#pragma unroll
    for (int ni = 0; ni < 4; ++ni)
        bv[ni] = bias[col0 + wn + ni * 16 + lr];
#pragma unroll
    for (int mi = 0; mi < 4; ++mi) {
#pragma unroll
        for (int j = 0; j < 4; ++j) {
            const long long row = (long long)row0 + wm + mi * 16 + lg * 4 + j;
            float* op = out + row * V_DIM + col0 + wn;
#pragma unroll
            for (int ni = 0; ni < 4; ++ni)
                __builtin_nontemporal_store(acc[mi][ni][j] + bv[ni], &op[ni * 16 + lr]);
        }
    }
}

// ---- fused fallback (proven r3/r6) for small workspace ----
__global__ __launch_bounds__(512, 2)
void joiner_kernel(const float* __restrict__ enc, const int* __restrict__ prefix,
                   const float* __restrict__ emb, const unsigned short* __restrict__ wbf,
                   const float* __restrict__ bias, float* __restrict__ out) {
    __shared__ unsigned short A_s[M_TILE * 512];
    const int tid = threadIdx.x;
    const long long g0 = (long long)blockIdx.x * M_TILE;
    {
        const int r = tid >> 3, q = tid & 7;
        const float *encp, *embp;
        row_ptrs((int)g0 + r, enc, prefix, emb, &encp, &embp);
        const int r7 = r & 7;
#pragma unroll
        for (int jj = 0; jj < 8; ++jj) {
            const int d = q * 8 + jj * 64;
            float4 e0 = *reinterpret_cast<const float4*>(encp + d);
            float4 e1 = *reinterpret_cast<const float4*>(encp + d + 4);
            float4 p0 = *reinterpret_cast<const float4*>(embp + d);
            float4 p1 = *reinterpret_cast<const float4*>(embp + d + 4);
            bf16x8 pk;
            pk[0] = (short)f2bf(fast_tanh(e0.x + p0.x));
            pk[1] = (short)f2bf(fast_tanh(e0.y + p0.y));
            pk[2] = (short)f2bf(fast_tanh(e0.z + p0.z));
            pk[3] = (short)f2bf(fast_tanh(e0.w + p0.w));
            pk[4] = (short)f2bf(fast_tanh(e1.x + p1.x));
            pk[5] = (short)f2bf(fast_tanh(e1.y + p1.y));
            pk[6] = (short)f2bf(fast_tanh(e1.z + p1.z));
            pk[7] = (short)f2bf(fast_tanh(e1.w + p1.w));
            const int chunk = (q + 8 * jj) ^ r7;
            *reinterpret_cast<bf16x8*>(&A_s[r * 512 + chunk * 8]) = pk;
        }
    }
    __syncthreads();
    const int lane = tid & 63, wid = tid >> 6;
    const int wn = wid * 128, lr = lane & 15, lg = lane >> 4;
    const unsigned short* wb = wbf + (size_t)(wn + lr) * D_DIM + lg * 8;
    f32x4 acc[4][8];
#pragma unroll
    for (int mi = 0; mi < 4; ++mi)
#pragma unroll
        for (int ni = 0; ni < 8; ++ni) acc[mi][ni] = (f32x4){0.f, 0.f, 0.f, 0.f};
    bf16x8 bb[2][8];
#pragma unroll
    for (int ni = 0; ni < 8; ++ni)
        bb[0][ni] = *reinterpret_cast<const bf16x8*>(wb + ni * 16 * D_DIM);
#pragma unroll
    for (int s = 0; s < 16; ++s) {
        const int cur = s & 1, nxt = cur ^ 1;
        if (s < 15) {
#pragma unroll
            for (int ni = 0; ni < 8; ++ni)
                bb[nxt][ni] = *reinterpret_cast<const bf16x8*>(wb + ni * 16 * D_DIM + (s + 1) * 32);
        }
        bf16x8 af[4];
#pragma unroll
        for (int mi = 0; mi < 4; ++mi) {
            const int row = mi * 16 + lr;
            const int chunk = (s * 4 + lg) ^ (row & 7);
            af[mi] = *reinterpret_cast<const bf16x8*>(&A_s[row * 512 + chunk * 8]);
        }
#pragma unroll
        for (int mi = 0; mi < 4; ++mi)
#pragma unroll
            for (int ni = 0; ni < 8; ++ni)
                acc[mi][ni] = __builtin_amdgcn_mfma_f32_16x16x32_bf16(af[mi], bb[cur][ni], acc[mi][ni], 0, 0, 0);
    }
    float bv[8];
#pragma unroll
    for (int ni = 0; ni < 8; ++ni) bv[ni] = bias[wn + ni * 16 + lr];
#pragma unroll
    for (int mi = 0; mi < 4; ++mi) {
#pragma unroll
        for (int j = 0; j < 4; ++j) {
            const long long row = g0 + mi * 16 + lg * 4 + j;
            float* op = out + row * V_DIM + wn;
#pragma unroll
            for (int ni = 0; ni < 8; ++ni)
                op[ni * 16 + lr] = acc[mi][ni][j] + bv[ni];
        }
    }
}

extern "C" void kernel_launch(void* const* d_in, const int* in_sizes, int n_in,
                              void* d_out, int out_size, void* d_ws, size_t ws_size,
                              hipStream_t stream) {
    const float* enc    = (const float*)d_in[0];   // (8,200,512) f32
    const int*   prefix = (const int*)d_in[1];     // (8,100) int
    const float* emb    = (const float*)d_in[2];   // (1024,512) f32
    const float* jw     = (const float*)d_in[3];   // (1024,512) f32
    const float* jb     = (const float*)d_in[4];   // (1024,) f32
    float* out = (float*)d_out;                    // (8,200,100,1024) f32

    unsigned short* wbf = (unsigned short*)d_ws;   // ws[0..1MB): W bf16 row-major
    const size_t WB = (size_t)V_DIM * D_DIM * sizeof(unsigned short);
    const size_t AB = (size_t)M_TOTAL * D_DIM * sizeof(unsigned short);  // 164 MB
    unsigned short* Abf = wbf + (size_t)V_DIM * D_DIM;

    if (ws_size >= WB + AB) {                      // champion: merged prep + 128^2 GEMM
        prep_kernel<<<A_BLOCKS + W_BLOCKS, 512, 0, stream>>>(enc, prefix, emb, jw, Abf,
                                                             (ushort4*)wbf, A_BLOCKS);
        gemm128_kernel<<<10000, 256, 0, stream>>>(Abf, wbf, jb, out);
    } else {                                       // fused fallback (proven 382/420 us)
        prep_kernel<<<W_BLOCKS, 512, 0, stream>>>(enc, prefix, emb, jw, Abf, (ushort4*)wbf, 0);
        joiner_kernel<<<M_TOTAL / M_TILE, 512, 0, stream>>>(enc, prefix, emb, wbf, jb, out);
    }
}